// Round 6
// baseline (127.759 us; speedup 1.0000x reference)
//
#include <hip/hip_runtime.h>
#include <math.h>

// Problem constants (setup_inputs: S=2048, U=10, D=256)
#define SS   2048
#define UU   10
#define DD   256
#define BB   (SS * UU)   // 20480 rows
#define EPSF 1e-8f

typedef __attribute__((ext_vector_type(8))) short   bf16x8;
typedef __attribute__((ext_vector_type(4))) float   floatx4;

__device__ static inline unsigned short f2bf(float f) {
    union { float f; unsigned u; } v; v.f = f;
    unsigned r = (v.u + 0x7FFFu + ((v.u >> 16) & 1u)) >> 16;  // RNE
    return (unsigned short)r;
}

__device__ static inline void gl_lds16(const unsigned short* g, unsigned short* l) {
    // 16B per lane; LDS dest = wave-uniform base + lane*16
    __builtin_amdgcn_global_load_lds((const __attribute__((address_space(1))) void*)g,
                                     (__attribute__((address_space(3))) void*)l, 16, 0, 0);
}

// ---- Kernel 1 (fused prep): normalize rows -> Enb, centroid+normalize -> Cnb,
//      zero sumexp and out (no memset dispatch) ----
__global__ __launch_bounds__(256) void prep_kernel(const float* __restrict__ E,
                                                   unsigned short* __restrict__ Enb,
                                                   unsigned short* __restrict__ Cnb,
                                                   float* __restrict__ sumexp,
                                                   float* __restrict__ out) {
    const int s   = blockIdx.x;
    const int wid = threadIdx.x >> 6, lane = threadIdx.x & 63;
    __shared__ float cent[4][256];
    __shared__ float sred[256];

    if (threadIdx.x < UU) sumexp[s * UU + threadIdx.x] = 0.f;
    if (s == 0 && threadIdx.x == 0) out[0] = 0.f;

    float cp0 = 0.f, cp1 = 0.f, cp2 = 0.f, cp3 = 0.f;
    for (int u = wid; u < UU; u += 4) {
        const size_t roff = (size_t)(s * UU + u) * DD;
        float4 v = ((const float4*)(E + roff))[lane];
        float ssq = v.x * v.x + v.y * v.y + v.z * v.z + v.w * v.w;
#pragma unroll
        for (int off = 32; off; off >>= 1) ssq += __shfl_xor(ssq, off, 64);
        const float rinv = 1.0f / fmaxf(sqrtf(ssq), EPSF);
        ushort4 o;
        o.x = f2bf(v.x * rinv); o.y = f2bf(v.y * rinv);
        o.z = f2bf(v.z * rinv); o.w = f2bf(v.w * rinv);
        ((ushort4*)(Enb + roff))[lane] = o;
        cp0 += v.x; cp1 += v.y; cp2 += v.z; cp3 += v.w;
    }
    cent[wid][lane * 4 + 0] = cp0;
    cent[wid][lane * 4 + 1] = cp1;
    cent[wid][lane * 4 + 2] = cp2;
    cent[wid][lane * 4 + 3] = cp3;
    __syncthreads();

    const int d = threadIdx.x;
    const float c = (cent[0][d] + cent[1][d] + cent[2][d] + cent[3][d]) * 0.1f;
    sred[d] = c * c;
    __syncthreads();
#pragma unroll
    for (int off = 128; off; off >>= 1) {
        if (d < off) sred[d] += sred[d + off];
        __syncthreads();
    }
    const float rinv = 1.0f / fmaxf(sqrtf(sred[0]), EPSF);
    Cnb[(size_t)s * DD + d] = f2bf(c * rinv);
}

// ---- Kernel 2: barrier-free-K-loop bf16 MFMA GEMM + exp-sum + pos ----
// Block 256x64 (512 thr, 8 waves stacked in m; wave tile 32x64 = 2x4 of
// 16x16x32). B-tile (64 x 256 = 32 KB) resident in LDS for the whole block;
// ONE barrier total. A streamed global->VGPR fragments, prefetched 1 step.
#define BM 256
#define BN 64

__global__ __launch_bounds__(512, 4) void gemm_lse_kernel(const unsigned short* __restrict__ Enb,
                                                          const unsigned short* __restrict__ Cnb,
                                                          float* __restrict__ posArr,
                                                          float* __restrict__ sumexp) {
    __shared__ unsigned short Bs[BN * DD];   // 32 KB, granule slot = g ^ (row&7)

    const int tid  = threadIdx.x;
    const int wid  = tid >> 6, lane = tid & 63;
    const int l15  = lane & 15, quad = lane >> 4;

    const int bn = blockIdx.x & 31;          // SS/BN = 32
    const int bm = blockIdx.x >> 5;          // BB/BM = 80
    const int row0 = bm * BM, n0 = bn * BN;

    // ---- stage B once: 64 rows x 256 k. Each wave: 8 rows via 4 gl_lds16.
    // lane -> local row pair (l>>5), slot l&31 holds granule (l&31)^(row&7).
    {
        const int rloc = lane >> 5;              // 0/1 within the 2-row chunk
        const int slot = lane & 31;
#pragma unroll
        for (int i = 0; i < 4; ++i) {
            const int r = wid * 8 + i * 2 + rloc;            // 0..63
            const int g = (slot ^ (r & 7)) * 8;              // logical elem offset
            gl_lds16(Cnb + (size_t)(n0 + r) * DD + g, Bs + (wid * 8 + i * 2) * DD);
        }
    }
    __syncthreads();   // the only barrier: B resident from here on

    // A fragment pointers: row = row0 + wid*32 + mt*16 + l15, k = quad*8 + 8j
    const unsigned short* ap[2];
#pragma unroll
    for (int mt = 0; mt < 2; ++mt)
        ap[mt] = Enb + (size_t)(row0 + wid * 32 + mt * 16 + l15) * DD + quad * 8;

    // B fragment LDS offsets per nt (granule re-derived per k-step)
    int brow[4];
#pragma unroll
    for (int nt = 0; nt < 4; ++nt) brow[nt] = nt * 16 + l15;

    floatx4 acc[2][4];
#pragma unroll
    for (int i = 0; i < 2; ++i)
#pragma unroll
        for (int j = 0; j < 4; ++j) acc[i][j] = (floatx4){0.f, 0.f, 0.f, 0.f};

    bf16x8 acur[2], anext[2];
#pragma unroll
    for (int mt = 0; mt < 2; ++mt) acur[mt] = *(const bf16x8*)(ap[mt]);

#pragma unroll
    for (int ks = 0; ks < 8; ++ks) {             // 8 steps x 32 k, no barriers
        bf16x8 bfr[4];
#pragma unroll
        for (int nt = 0; nt < 4; ++nt) {
            const int r  = brow[nt];
            const int sl = (ks * 4 + quad) ^ (r & 7);        // swizzled granule slot
            bfr[nt] = *(const bf16x8*)(Bs + r * DD + sl * 8);
        }
        if (ks < 7) {
#pragma unroll
            for (int mt = 0; mt < 2; ++mt)
                anext[mt] = *(const bf16x8*)(ap[mt] + (ks + 1) * 32);
        }
#pragma unroll
        for (int mt = 0; mt < 2; ++mt)
#pragma unroll
            for (int nt = 0; nt < 4; ++nt)
                acc[mt][nt] = __builtin_amdgcn_mfma_f32_16x16x32_bf16(acur[mt], bfr[nt], acc[mt][nt], 0, 0, 0);
#pragma unroll
        for (int mt = 0; mt < 2; ++mt) acur[mt] = anext[mt];
    }

    // epilogue: C/D layout col=l15 (n), row=quad*4+reg (m)
#pragma unroll
    for (int mt = 0; mt < 2; ++mt) {
        float rs[4] = {0.f, 0.f, 0.f, 0.f};
        const int growb = row0 + wid * 32 + mt * 16 + quad * 4;
#pragma unroll
        for (int nt = 0; nt < 4; ++nt) {
            const int col = n0 + nt * 16 + l15;
#pragma unroll
            for (int r = 0; r < 4; ++r) {
                const int grow = growb + r;
                const float sim = acc[mt][nt][r];
                if (col == grow / UU) {
                    posArr[grow] = sim;           // excluded from sum (-inf mask)
                } else {
                    rs[r] += __expf(sim);
                }
            }
        }
#pragma unroll
        for (int m = 1; m < 16; m <<= 1) {
#pragma unroll
            for (int r = 0; r < 4; ++r) rs[r] += __shfl_xor(rs[r], m, 64);
        }
        if (l15 == 0) {
#pragma unroll
            for (int r = 0; r < 4; ++r) atomicAdd(&sumexp[growb + r], rs[r]);
        }
    }
}

// ---- Kernel 3: single-pass finalize: mean of (-pos + log(sumexp)) ----
__global__ __launch_bounds__(256) void finalize_kernel(const float* __restrict__ posArr,
                                                       const float* __restrict__ sumexp,
                                                       float* __restrict__ out) {
    __shared__ float sred[256];
    const int tid = threadIdx.x;
    const int r = blockIdx.x * 256 + tid;
    sred[tid] = logf(sumexp[r]) - posArr[r];
    __syncthreads();
#pragma unroll
    for (int off = 128; off; off >>= 1) {
        if (tid < off) sred[tid] += sred[tid + off];
        __syncthreads();
    }
    if (tid == 0) atomicAdd(out, sred[0] * (1.0f / (float)BB));
}

extern "C" void kernel_launch(void* const* d_in, const int* in_sizes, int n_in,
                              void* d_out, int out_size, void* d_ws, size_t ws_size,
                              hipStream_t stream) {
    const float* E = (const float*)d_in[0];
    float* out = (float*)d_out;

    unsigned short* Enb = (unsigned short*)d_ws;            // BB*DD bf16 = 10.5 MB
    unsigned short* Cnb = Enb + (size_t)BB * DD;            // SS*DD bf16 = 1 MB
    float* posArr = (float*)(Cnb + (size_t)SS * DD);        // BB floats
    float* sumexp = posArr + BB;                            // BB floats (zeroed by prep)

    prep_kernel<<<SS, 256, 0, stream>>>(E, Enb, Cnb, sumexp, out);
    gemm_lse_kernel<<<(BB / BM) * (SS / BN), 512, 0, stream>>>(Enb, Cnb, posArr, sumexp);
    finalize_kernel<<<BB / 256, 256, 0, stream>>>(posArr, sumexp, out);
}

// Round 7
// 116.401 us; speedup vs baseline: 1.0976x; 1.0976x over previous
//
#include <hip/hip_runtime.h>
#include <math.h>

// Problem constants (setup_inputs: S=2048, U=10, D=256)
#define SS   2048
#define UU   10
#define DD   256
#define BB   (SS * UU)   // 20480 rows
#define EPSF 1e-8f

typedef __attribute__((ext_vector_type(8))) short   bf16x8;
typedef __attribute__((ext_vector_type(4))) float   floatx4;

__device__ static inline unsigned short f2bf(float f) {
    union { float f; unsigned u; } v; v.f = f;
    unsigned r = (v.u + 0x7FFFu + ((v.u >> 16) & 1u)) >> 16;  // RNE
    return (unsigned short)r;
}

__device__ static inline void gl_lds16(const unsigned short* g, unsigned short* l) {
    // 16B per lane; LDS dest = wave-uniform base + lane*16
    __builtin_amdgcn_global_load_lds((const __attribute__((address_space(1))) void*)g,
                                     (__attribute__((address_space(3))) void*)l, 16, 0, 0);
}

// ---- Kernel 1: barrier-free prep, one dispatch ----
// blocks [0, BB/4): one wave per row -> normalize to bf16, zero sumexp
// blocks [BB/4, BB/4+SS/4): one wave per speaker -> centroid+normalize to bf16
#define NORM_NBLK (BB / 4)   // 5120
#define CENT_NBLK (SS / 4)   // 512

__global__ __launch_bounds__(256) void prep_kernel(const float* __restrict__ E,
                                                   unsigned short* __restrict__ Enb,
                                                   unsigned short* __restrict__ Cnb,
                                                   float* __restrict__ sumexp,
                                                   float* __restrict__ out) {
    const int wid = threadIdx.x >> 6, lane = threadIdx.x & 63;
    const int b = blockIdx.x;

    if (b < NORM_NBLK) {
        const int row = b * 4 + wid;
        const float4 v = ((const float4*)(E + (size_t)row * DD))[lane];
        float ssq = v.x * v.x + v.y * v.y + v.z * v.z + v.w * v.w;
#pragma unroll
        for (int off = 32; off; off >>= 1) ssq += __shfl_xor(ssq, off, 64);
        const float rinv = 1.0f / fmaxf(sqrtf(ssq), EPSF);
        ushort4 o;
        o.x = f2bf(v.x * rinv); o.y = f2bf(v.y * rinv);
        o.z = f2bf(v.z * rinv); o.w = f2bf(v.w * rinv);
        ((ushort4*)(Enb + (size_t)row * DD))[lane] = o;
        if (lane == 0) {
            sumexp[row] = 0.f;
            if (row == 0) out[0] = 0.f;
        }
    } else {
        const int s = (b - NORM_NBLK) * 4 + wid;
        const float* base = E + (size_t)s * UU * DD + lane * 4;
        float4 c = {0.f, 0.f, 0.f, 0.f};
#pragma unroll
        for (int u = 0; u < UU; ++u) {
            const float4 v = *(const float4*)(base + u * DD);
            c.x += v.x; c.y += v.y; c.z += v.z; c.w += v.w;
        }
        c.x *= 0.1f; c.y *= 0.1f; c.z *= 0.1f; c.w *= 0.1f;
        float ssq = c.x * c.x + c.y * c.y + c.z * c.z + c.w * c.w;
#pragma unroll
        for (int off = 32; off; off >>= 1) ssq += __shfl_xor(ssq, off, 64);
        const float rinv = 1.0f / fmaxf(sqrtf(ssq), EPSF);
        ushort4 o;
        o.x = f2bf(c.x * rinv); o.y = f2bf(c.y * rinv);
        o.z = f2bf(c.z * rinv); o.w = f2bf(c.w * rinv);
        ((ushort4*)(Cnb + (size_t)s * DD))[lane] = o;
    }
}

// ---- Kernel 2: bf16 MFMA GEMM (Enb x Cnb^T) fused with exp-sum + pos ----
// Round-5 core (best measured, 0 conflicts): 128x128 block, 2x2 waves, wave
// 64x64 = 4x4 tiles of 16x16x32, BK=32, granule swizzle slot = g ^ ((r>>1)&3).
#define BM 128
#define BN 128
#define BK 32

__global__ __launch_bounds__(256) void gemm_lse_kernel(const unsigned short* __restrict__ Enb,
                                                       const unsigned short* __restrict__ Cnb,
                                                       float* __restrict__ posArr,
                                                       float* __restrict__ sumexp) {
    __shared__ unsigned short As[BM * BK];   // 8 KB, [row][32k] with swizzled granules
    __shared__ unsigned short Bs[BN * BK];   // 8 KB

    const int tid  = threadIdx.x;
    const int wid  = tid >> 6, lane = tid & 63;
    const int l15  = lane & 15, quad = lane >> 4;
    const int wave_m = wid >> 1, wave_n = wid & 1;

    const int bn = blockIdx.x & 15;          // SS/BN = 16 (bm-grouped order)
    const int bm = blockIdx.x >> 4;          // BB/BM = 160
    const int row0 = bm * BM, n0 = bn * BN;

    // staging: 16 chunks of 1 KB (16 rows x 32k); A: c=0..7, B: c=8..15; 4/wave.
    // lane -> row rl=lane>>2, slot sl=lane&3; fetch logical granule sl^((rl>>1)&3)
    const int rl = lane >> 2;
    const int gf = ((lane & 3) ^ ((rl >> 1) & 3)) * 8;
    const unsigned short* gp[4];
    unsigned short* lp[4];
#pragma unroll
    for (int i = 0; i < 4; ++i) {
        const int c = wid * 4 + i;
        if (c < 8) {
            gp[i] = Enb + (size_t)(row0 + c * 16 + rl) * DD + gf;
            lp[i] = As + c * 512;
        } else {
            gp[i] = Cnb + (size_t)(n0 + (c - 8) * 16 + rl) * DD + gf;
            lp[i] = Bs + (c - 8) * 512;
        }
    }

    // fragment offsets: row r = wtile*16 + l15, elem = r*BK + (quad^((l15>>1)&3))*8
    const int fswz = (quad ^ ((l15 >> 1) & 3)) * 8;
    int aoff[4], boff[4];
#pragma unroll
    for (int t = 0; t < 4; ++t) {
        aoff[t] = (wave_m * 64 + t * 16 + l15) * BK + fswz;
        boff[t] = (wave_n * 64 + t * 16 + l15) * BK + fswz;
    }

    floatx4 acc[4][4];
#pragma unroll
    for (int i = 0; i < 4; ++i)
#pragma unroll
        for (int j = 0; j < 4; ++j) acc[i][j] = (floatx4){0.f, 0.f, 0.f, 0.f};

    for (int k0 = 0; k0 < DD; k0 += BK) {
        __syncthreads();                      // prior stage's LDS reads done
#pragma unroll
        for (int i = 0; i < 4; ++i) gl_lds16(gp[i] + k0, lp[i]);
        __syncthreads();                      // vmcnt drained: tiles landed

        bf16x8 af[4], bfr[4];
#pragma unroll
        for (int t = 0; t < 4; ++t) af[t]  = *(const bf16x8*)(As + aoff[t]);
#pragma unroll
        for (int t = 0; t < 4; ++t) bfr[t] = *(const bf16x8*)(Bs + boff[t]);
#pragma unroll
        for (int mt = 0; mt < 4; ++mt)
#pragma unroll
            for (int nt = 0; nt < 4; ++nt)
                acc[mt][nt] = __builtin_amdgcn_mfma_f32_16x16x32_bf16(af[mt], bfr[nt], acc[mt][nt], 0, 0, 0);
    }

    // epilogue: C/D layout col=l15 (n), row=quad*4+reg (m)
#pragma unroll
    for (int mt = 0; mt < 4; ++mt) {
        float rs[4] = {0.f, 0.f, 0.f, 0.f};
        const int growb = row0 + wave_m * 64 + mt * 16 + quad * 4;
#pragma unroll
        for (int nt = 0; nt < 4; ++nt) {
            const int col = n0 + wave_n * 64 + nt * 16 + l15;
#pragma unroll
            for (int r = 0; r < 4; ++r) {
                const int grow = growb + r;
                const float sim = acc[mt][nt][r];
                if (col == grow / UU) {
                    posArr[grow] = sim;           // excluded from sum (-inf mask)
                } else {
                    rs[r] += __expf(sim);
                }
            }
        }
#pragma unroll
        for (int m = 1; m < 16; m <<= 1) {
#pragma unroll
            for (int r = 0; r < 4; ++r) rs[r] += __shfl_xor(rs[r], m, 64);
        }
        if (l15 == 0) {
#pragma unroll
            for (int r = 0; r < 4; ++r) atomicAdd(&sumexp[growb + r], rs[r]);
        }
    }
}

// ---- Kernel 3: single-pass finalize: mean of (-pos + log(sumexp)) ----
__global__ __launch_bounds__(256) void finalize_kernel(const float* __restrict__ posArr,
                                                       const float* __restrict__ sumexp,
                                                       float* __restrict__ out) {
    __shared__ float sred[256];
    const int tid = threadIdx.x;
    const int r = blockIdx.x * 256 + tid;
    sred[tid] = __logf(sumexp[r]) - posArr[r];
    __syncthreads();
#pragma unroll
    for (int off = 128; off; off >>= 1) {
        if (tid < off) sred[tid] += sred[tid + off];
        __syncthreads();
    }
    if (tid == 0) atomicAdd(out, sred[0] * (1.0f / (float)BB));
}

extern "C" void kernel_launch(void* const* d_in, const int* in_sizes, int n_in,
                              void* d_out, int out_size, void* d_ws, size_t ws_size,
                              hipStream_t stream) {
    const float* E = (const float*)d_in[0];
    float* out = (float*)d_out;

    unsigned short* Enb = (unsigned short*)d_ws;            // BB*DD bf16 = 10.5 MB
    unsigned short* Cnb = Enb + (size_t)BB * DD;            // SS*DD bf16 = 1 MB
    float* posArr = (float*)(Cnb + (size_t)SS * DD);        // BB floats
    float* sumexp = posArr + BB;                            // BB floats (zeroed by prep)

    prep_kernel<<<NORM_NBLK + CENT_NBLK, 256, 0, stream>>>(E, Enb, Cnb, sumexp, out);
    gemm_lse_kernel<<<(BB / BM) * (SS / BN), 256, 0, stream>>>(Enb, Cnb, posArr, sumexp);
    finalize_kernel<<<BB / 256, 256, 0, stream>>>(posArr, sumexp, out);
}